// Round 10
// baseline (269.201 us; speedup 1.0000x reference)
//
#include <hip/hip_runtime.h>
#include <math.h>

#define LEAKC 0.2f

#define NB 4
#define NC 64
#define LLEN 16384
#define HW 2304
#define PP 54          // padded pitch (48 + 2*3)
#define PHW 2916       // 54*54
#define SLABP 72       // slab c-pitch: 2-way max conflicts (free per m136)
#define CP 72          // ie1 LDS c-pitch
#define IE1C 50        // ie1 LDS cols (padded img cols 2..51)

typedef __attribute__((ext_vector_type(8))) short short8;
typedef __attribute__((ext_vector_type(4))) float floatx4;

__device__ __forceinline__ float leaky(float x){ return x > 0.f ? x : LEAKC*x; }

__device__ __forceinline__ float wave_sum64(float v){
  for(int off=32;off;off>>=1) v += __shfl_xor(v,off);
  return v;
}

__device__ __forceinline__ unsigned short f2bf(float x){
  unsigned u=__float_as_uint(x);
  unsigned r=u+0x7FFFu+((u>>16)&1u);
  return (unsigned short)(r>>16);
}

__device__ __forceinline__ void threefry2x32(unsigned k0, unsigned k1, unsigned& x0, unsigned& x1){
  unsigned ks0=k0, ks1=k1, ks2=k0^k1^0x1BD11BDAu;
  x0+=ks0; x1+=ks1;
  const int rot0[4]={13,15,26,6};
  const int rot1[4]={17,29,16,24};
#define TF_APPLY(rr) {for(int r=0;r<4;r++){x0+=x1; x1=(x1<<rr[r])|(x1>>(32-rr[r])); x1^=x0;}}
  TF_APPLY(rot0); x0+=ks1; x1+=ks2+1u;
  TF_APPLY(rot1); x0+=ks2; x1+=ks0+2u;
  TF_APPLY(rot0); x0+=ks0; x1+=ks1+3u;
  TF_APPLY(rot1); x0+=ks1; x1+=ks2+4u;
  TF_APPLY(rot0); x0+=ks2; x1+=ks0+5u;
#undef TF_APPLY
}

__device__ __forceinline__ float jax_uniform128(int i){
  unsigned x0=0u, x1=(unsigned)i;
  threefry2x32(0u,42u,x0,x1);
  unsigned bits = x0 ^ x1;
  unsigned fb=(bits>>9)|0x3f800000u;
  float f=__uint_as_float(fb)-1.0f;
  float u=f*(1.0f-1e-10f)+1e-10f;
  return fmaxf(1e-10f,u);
}

struct MidSM {
  float sT[64], s0[64], sL[64];
  float red8[64][9];
  float totA_s[4]; float rms_s;
  float part[512];
  float te_s[128], t1_s[8];
  float f1[16], h[64], tif[128], tifn[128], tden[8], pden[4], pn[64], z[32];
  int sidx[8], sfirst[4], srank[8];
  float fbuf[256], hh[64], ffn_s[256], finv_s;
  float scores[64];
  int order[64];
};

// ---------------- k_pre: stats partials (0..255) + padded imgT (256..399) + weight prep (400..867)
//                  + L3 warm (868..931) + imgTP halo zero + counter zero (932..947) ----------------
__global__ __launch_bounds__(256) void k_pre(const float* __restrict__ task_f,
                      const float* __restrict__ w1A, const float* __restrict__ w1B,
                      float* __restrict__ totApart, float* __restrict__ a0A, float* __restrict__ aLA,
                      float* __restrict__ totBpart, float* __restrict__ a0B, float* __restrict__ aLB,
                      float* __restrict__ rmspart,
                      const float* __restrict__ img,
                      const float* __restrict__ w1, const float* __restrict__ w2,
                      const float* __restrict__ wa,
                      unsigned short* __restrict__ imgTP,
                      unsigned short* __restrict__ W1T, unsigned short* __restrict__ W2T,
                      unsigned short* __restrict__ WAT,
                      const float* __restrict__ mw1, const float* __restrict__ mw3,
                      const float* __restrict__ bvw1p, const float* __restrict__ bvw2p,
                      const float* __restrict__ bvt2p, const float* __restrict__ atw2p,
                      const float* __restrict__ bankp,
                      const float* __restrict__ m1w2p, const float* __restrict__ m3w2p,
                      const float* __restrict__ zcwp,
                      float* __restrict__ warm, int* __restrict__ cnt){
  if(blockIdx.x<256){
    int b=blockIdx.x>>6, seg=blockIdx.x&63;
    const float* x=task_f+b*LLEN;
    float tA[4]={0,0,0,0};
    float tB[64];
#pragma unroll
    for(int c=0;c<64;c++) tB[c]=0.f;
    float sq=0.f;
    int l=seg*256+threadIdx.x;
    {
      float xm=(l>0)?x[l-1]:0.f;
      float xc=x[l];
      float xp=(l<LLEN-1)?x[l+1]:0.f;
      sq=xc*xc;
#pragma unroll
      for(int c=0;c<4;c++){
        float a=leaky(w1A[c*3+0]*xm + w1A[c*3+1]*xc + w1A[c*3+2]*xp);
        tA[c]=a;
        if(l==0) a0A[b*4+c]=a;
        if(l==LLEN-1) aLA[b*4+c]=a;
      }
#pragma unroll
      for(int c=0;c<64;c++){
        float a=leaky(w1B[c*3+0]*xm + w1B[c*3+1]*xc + w1B[c*3+2]*xp);
        tB[c]=a;
        if(l==0) a0B[b*64+c]=a;
        if(l==LLEN-1) aLB[b*64+c]=a;
      }
    }
    sq=wave_sum64(sq);
#pragma unroll
    for(int c=0;c<4;c++) tA[c]=wave_sum64(tA[c]);
#pragma unroll
    for(int c=0;c<64;c++){
      float v=tB[c];
      for(int off=32;off;off>>=1) v+=__shfl_down(v,off);
      tB[c]=v;
    }
    __shared__ float redB[4][64];
    __shared__ float redA[4][4];
    __shared__ float redQ[4];
    int wave=threadIdx.x>>6, lane=threadIdx.x&63;
    if(lane==0){
#pragma unroll
      for(int c=0;c<64;c++) redB[wave][c]=tB[c];
#pragma unroll
      for(int c=0;c<4;c++) redA[wave][c]=tA[c];
      redQ[wave]=sq;
    }
    __syncthreads();
    if(threadIdx.x<64){
      float s=redB[0][threadIdx.x]+redB[1][threadIdx.x]+redB[2][threadIdx.x]+redB[3][threadIdx.x];
      totBpart[(size_t)(b*64+seg)*64+threadIdx.x]=s;
    } else if(threadIdx.x<68){
      int c=threadIdx.x-64;
      totApart[(b*64+seg)*4+c]=redA[0][c]+redA[1][c]+redA[2][c]+redA[3][c];
    } else if(threadIdx.x==68){
      rmspart[b*64+seg]=redQ[0]+redQ[1]+redQ[2]+redQ[3];
    }
  } else if(blockIdx.x<400){
    int blk=blockIdx.x-256;
    int b=blk/36, t=blk%36;
    int p0=t*64;
    __shared__ float tile[64][65];
    int pp=threadIdx.x&63, c4=threadIdx.x>>6;
    for(int r=0;r<16;r++){
      int c=c4*16+r;
      tile[c][pp]=img[(b*64+c)*HW + p0+pp];
    }
    __syncthreads();
    int pxl=threadIdx.x>>2, cg=(threadIdx.x&3)*16;
    unsigned out[8];
#pragma unroll
    for(int q=0;q<8;q++){
      unsigned lo=f2bf(tile[cg+2*q][pxl]);
      unsigned hi=f2bf(tile[cg+2*q+1][pxl]);
      out[q]=lo|(hi<<16);
    }
    int px=p0+pxl;
    int h=px/48, w=px-h*48;
    int poff=(h+3)*PP+(w+3);
    unsigned* dst=(unsigned*)(imgTP + ((size_t)(b*PHW+poff))*64 + cg);
#pragma unroll
    for(int q=0;q<8;q++) dst[q]=out[q];
  } else if(blockIdx.x<868){
    int n=(blockIdx.x-400)*256+threadIdx.x;
    if(n<9*64*64){
      int tap=n>>12, oc=(n>>6)&63, c=n&63;
      W1T[n]=f2bf(w1[oc*576+c*9+tap]);
    } else if(n<9*64*64+9*128*64){
      int m=n-9*64*64;
      int tap=m/8192, r=m-tap*8192, oc=r>>6, c=r&63;
      W2T[m]=f2bf(w2[oc*576+c*9+tap]);
    } else {
      int q=n-9*64*64-9*128*64;
      if(q<9*16*64){
        int tap=q>>10, r=q&1023, o=r>>6, c=r&63;
        WAT[q]=(o<8)?f2bf(wa[o*576+c*9+tap]):(unsigned short)0;
      }
    }
  } else if(blockIdx.x<932){
    // ---- L3 warm (64 blocks = 16384 threads): later-kernel weights -> L3 ----
    int t=(blockIdx.x-868)*256+threadIdx.x;
    float a=0.f;
    for(int i=t;i*16<16384;i+=16384) a+=mw1[i*16];
    for(int i=t;i*16<16384;i+=16384) a+=mw3[i*16];
    for(int i=t;i*16<16384;i+=16384) a+=bvw1p[i*16];
    for(int i=t;i*16<16384;i+=16384) a+=bvw2p[i*16];
    for(int i=t;i*16<24576;i+=16384) a+=bvt2p[i*16];
    for(int i=t;i*16<8192;i+=16384) a+=atw2p[i*16];
    for(int i=t;i*16<16384;i+=16384) a+=bankp[i*16];
    for(int i=t;i*16<262144;i+=16384) a+=m1w2p[i*16];
    for(int i=t;i*16<2359296;i+=16384) a+=m3w2p[i*16];
    for(int i=t;i*16<4096;i+=16384) a+=zcwp[i*16];
    warm[t&1023]=a;
  } else {
    // imgTP halo zero: 612 halo px per b, 8 x uint4 chunks per px (+ counter zero)
    if(blockIdx.x==932 && threadIdx.x<4)
      __hip_atomic_store(&cnt[threadIdx.x],0,__ATOMIC_RELAXED,__HIP_MEMORY_SCOPE_AGENT);
    int id=(blockIdx.x-932)*256+threadIdx.x;   // 4096 threads
    uint4 z=make_uint4(0,0,0,0);
    for(int cch=id;cch<19584;cch+=4096){
      int ck=cch&7, pxid=cch>>3;               // pxid 0..2447
      int b=pxid/612, p=pxid-b*612;
      int h,w;
      if(p<324){ int r=p/54; w=p-r*54; h=(r<3)?r:(r+48); }
      else { int q=p-324; int r2=q/6; int cc=q-r2*6; h=3+r2; w=(cc<3)?cc:(cc+48); }
      *(uint4*)(imgTP + ((size_t)(b*PHW + h*PP + w))*64 + ck*8)=z;
    }
  }
}

// =========== k_cm: conv12 (0..95, release cnt[0]) + iA (96..107, release cnt[1])
//             + mid (108..111, gate1 cnt[1]>=12 / gate2 cnt[0]>=96, tail exported) ===========
__global__ __launch_bounds__(512) void k_cm(const unsigned short* __restrict__ imgTP,
    const unsigned short* __restrict__ W1T, const unsigned short* __restrict__ W2T,
    const unsigned short* __restrict__ WAT,
    const float* __restrict__ bn1, const float* __restrict__ bn2, const float* __restrict__ bnA,
    float* __restrict__ iepart, float* __restrict__ i1part,
    const float* __restrict__ totApart, const float* __restrict__ a0A, const float* __restrict__ aLA,
    const float* __restrict__ totBpart, const float* __restrict__ a0B, const float* __restrict__ aLB,
    const float* __restrict__ rmspart,
    const float* __restrict__ tA_w2, const float* __restrict__ bv_t2,
    const float* __restrict__ at_w1, const float* __restrict__ at_b1,
    const float* __restrict__ at_ln_g, const float* __restrict__ at_ln_b,
    const float* __restrict__ at_w2, const float* __restrict__ at_b2,
    const float* __restrict__ protos,
    const float* __restrict__ bv_w1, const float* __restrict__ bv_b1,
    const float* __restrict__ bv_ln_g, const float* __restrict__ bv_ln_b,
    const float* __restrict__ bv_w2, const float* __restrict__ bv_b2,
    const float* __restrict__ bank,
    int* __restrict__ idxo, int* __restrict__ rowsp,
    int* __restrict__ cnt){
  __shared__ __align__(16) char smraw[75456];
  int tid=threadIdx.x;
  int lane=tid&63, wv=tid>>6;
  int n0=lane&15, kg=lane>>4;
  if(blockIdx.x<96){
    int blk=blockIdx.x;
    int b=blk/24, hp=blk-b*24;
    int h0=hp*2;
    unsigned short* slab=(unsigned short*)smraw;          // 6*54*SLABP shorts = 46656B
    unsigned short* ie1=(unsigned short*)(smraw+46656);   // 4*IE1C*CP shorts = 28800B
    {
      const unsigned short* ibase=imgTP+((size_t)b*PHW+(size_t)(h0+1)*PP)*64;
      for(int e=tid;e<6*54*8;e+=512){
        int rr=e/(54*8), rem=e-rr*54*8, w=rem>>3, ck=rem&7;
        uint4 v=*(const uint4*)(ibase+((size_t)(rr*PP+w))*64+ck*8);
        *(uint4*)(slab+(rr*54+w)*SLABP+ck*8)=v;
      }
      if(tid<64){  // zero-pad ie1 cols q=0 and q=49
        int br=tid>>4, cq=(tid>>3)&1, ck=tid&7;
        *(uint4*)(ie1+((size_t)(br*IE1C+(cq?49:0)))*CP+ck*8)=make_uint4(0,0,0,0);
      }
    }
    __syncthreads();
    // phase 1: conv1 (M=64 oc) -> ie1
    {
      int mt=wv&3, rh=wv>>2;
      floatx4 acc[2][3];
#pragma unroll
      for(int rr=0;rr<2;rr++)
#pragma unroll
        for(int nt=0;nt<3;nt++) acc[rr][nt]=(floatx4){0.f,0.f,0.f,0.f};
#pragma unroll
      for(int ti=0;ti<3;ti++){
#pragma unroll
        for(int tj=0;tj<3;tj++){
          int tap=ti*3+tj;
          const unsigned short* Ab=W1T+(size_t)tap*4096;
#pragma unroll
          for(int c0=0;c0<64;c0+=32){
            short8 a=*(const short8*)(Ab+((mt*16+n0)*64+c0+kg*8));
#pragma unroll
            for(int rr=0;rr<2;rr++){
              int sr=rh*2+rr+ti;
#pragma unroll
              for(int nt=0;nt<3;nt++){
                int sc=nt*16+n0+tj+2;
                short8 bv=*(const short8*)(slab+(sr*54+sc)*SLABP+c0+kg*8);
                acc[rr][nt]=__builtin_amdgcn_mfma_f32_16x16x32_bf16(a,bv,acc[rr][nt],0,0,0);
              }
            }
          }
        }
      }
      int obase=mt*16+kg*4;
      float scale[4],m_[4],be_[4];
#pragma unroll
      for(int reg=0;reg<4;reg++){
        int o=obase+reg;
        scale[reg]=bn1[o]/sqrtf(bn1[192+o]+1e-5f);
        m_[reg]=bn1[128+o]; be_[reg]=bn1[64+o];
      }
#pragma unroll
      for(int rr=0;rr<2;rr++){
        int br=rh*2+rr;
        bool rv=((unsigned)(h0-1+br))<48u;
#pragma unroll
        for(int nt=0;nt<3;nt++){
          float v0=rv?leaky((acc[rr][nt][0]-m_[0])*scale[0]+be_[0]):0.f;
          float v1=rv?leaky((acc[rr][nt][1]-m_[1])*scale[1]+be_[1]):0.f;
          float v2=rv?leaky((acc[rr][nt][2]-m_[2])*scale[2]+be_[2]):0.f;
          float v3=rv?leaky((acc[rr][nt][3]-m_[3])*scale[3]+be_[3]):0.f;
          unsigned w0=f2bf(v0)|((unsigned)f2bf(v1)<<16);
          unsigned w1=f2bf(v2)|((unsigned)f2bf(v3)<<16);
          uint2 pk={w0,w1};
          *(uint2*)(ie1+((size_t)(br*IE1C+(nt*16+1+n0)))*CP+obase)=pk;
        }
      }
    }
    __syncthreads();
    // phase 2: conv2 (M=128 oc) -> mean partial
    {
      int mt2=wv;
      floatx4 acc[6];
#pragma unroll
      for(int i=0;i<6;i++) acc[i]=(floatx4){0.f,0.f,0.f,0.f};
#pragma unroll
      for(int ti=0;ti<3;ti++){
#pragma unroll
        for(int tj=0;tj<3;tj++){
          int tap=ti*3+tj;
          const unsigned short* Ab=W2T+(size_t)tap*8192;
#pragma unroll
          for(int c0=0;c0<64;c0+=32){
            short8 a=*(const short8*)(Ab+((mt2*16+n0)*64+c0+kg*8));
#pragma unroll
            for(int rr=0;rr<2;rr++){
              int sr=rr+ti;
#pragma unroll
              for(int wc=0;wc<3;wc++){
                int q=wc*16+n0+tj;
                short8 bv=*(const short8*)(ie1+((size_t)(sr*IE1C+q))*CP+c0+kg*8);
                acc[rr*3+wc]=__builtin_amdgcn_mfma_f32_16x16x32_bf16(a,bv,acc[rr*3+wc],0,0,0);
              }
            }
          }
        }
      }
      int obase=mt2*16+kg*4;
#pragma unroll
      for(int reg=0;reg<4;reg++){
        int o=obase+reg;
        float scale=bn2[o]/sqrtf(bn2[384+o]+1e-5f);
        float m_=bn2[256+o], be_=bn2[128+o];
        float part=0;
#pragma unroll
        for(int i=0;i<6;i++) part+=leaky((acc[i][reg]-m_)*scale+be_);
        for(int off=1;off<16;off<<=1) part+=__shfl_xor(part,off);
        if(n0==0) iepart[(b*24+hp)*128+o]=part*(1.f/2304.f);
      }
    }
    __syncthreads();   // all stores drained (vmcnt before barrier)
    if(tid==0) __hip_atomic_fetch_add(&cnt[0],1,__ATOMIC_RELEASE,__HIP_MEMORY_SCOPE_AGENT);
  } else if(blockIdx.x<108){
    // iA branch: 12 blocks x 8 waves; wave handles one hp
    int blk2=blockIdx.x-96;
    int b=blk2/3, hg=blk2%3;
    int hp=hg*8+wv;
    int h0=hp*2;
    const unsigned short* ib=imgTP+(size_t)b*PHW*64;
    floatx4 acc[6];
#pragma unroll
    for(int i=0;i<6;i++) acc[i]=(floatx4){0.f,0.f,0.f,0.f};
#pragma unroll
    for(int ti=0;ti<3;ti++){
#pragma unroll
      for(int tj=0;tj<3;tj++){
        int tap=ti*3+tj;
        const unsigned short* Ab=WAT+(size_t)tap*1024;
#pragma unroll
        for(int c0=0;c0<64;c0+=32){
          short8 a=*(const short8*)(Ab+(n0*64+c0+kg*8));
#pragma unroll
          for(int rr=0;rr<2;rr++){
            int r=h0+rr+ti-1+3;
#pragma unroll
            for(int wc=0;wc<3;wc++){
              int w=wc*16+n0+tj-1+3;
              short8 bv=*(const short8*)(ib+((size_t)(r*PP+w)*64+c0+kg*8));
              acc[rr*3+wc]=__builtin_amdgcn_mfma_f32_16x16x32_bf16(a,bv,acc[rr*3+wc],0,0,0);
            }
          }
        }
      }
    }
    int obase=kg*4;
#pragma unroll
    for(int reg=0;reg<4;reg++){
      int o=obase+reg;
      float part=0;
      if(o<8){
        float scale=bnA[o]/sqrtf(bnA[24+o]+1e-5f);
        float m_=bnA[16+o], be_=bnA[8+o];
#pragma unroll
        for(int i=0;i<6;i++) part+=leaky((acc[i][reg]-m_)*scale+be_);
      }
      for(int off=1;off<16;off<<=1) part+=__shfl_xor(part,off);
      if(n0==0 && o<8) i1part[(b*24+hp)*8+o]=part*(1.f/2304.f);
    }
    __syncthreads();
    if(tid==0) __hip_atomic_fetch_add(&cnt[1],1,__ATOMIC_RELEASE,__HIP_MEMORY_SCOPE_AGENT);
  } else {
    // =================== MID (two-stage gating; ends at selection export) ===================
    MidSM* S=(MidSM*)smraw;
    int b=blockIdx.x-108;
    const float invL=1.0f/16384.0f;
    // entry: k_pre-derived reductions only (safe pre-gate)
    {
      int c8=tid>>3, g8=tid&7;
      float s8=0;
#pragma unroll
      for(int seg=g8*8;seg<g8*8+8;seg++) s8+=totBpart[(size_t)(b*64+seg)*64+c8];
      S->red8[c8][g8]=s8;
    }
    if(tid>=64 && tid<128){
      int t=tid-64;
      S->s0[t]=a0B[b*64+t]; S->sL[t]=aLB[b*64+t];
    } else if(tid>=128 && tid<192){
      float v=rmspart[b*64+(tid-128)];
      v=wave_sum64(v);
      if(tid==128) S->rms_s=v;
    } else if(tid>=192 && tid<196){
      int c=tid-192;
      float s=0;
#pragma unroll 8
      for(int seg=0;seg<64;seg++) s+=totApart[(b*64+seg)*4+c];
      S->totA_s[c]=s;
    }
    __syncthreads();
    if(tid<64){
      float s=0;
#pragma unroll
      for(int g=0;g<8;g++) s+=S->red8[tid][g];
      S->sT[tid]=s;
    }
    __syncthreads();
    float scB=1.0f/(sqrtf(S->rms_s*invL)+1e-8f);
    if(tid<256){
      int c2=tid&127, h2=tid>>7;
      const float* wr=bv_t2+c2*192;
      float s=0;
      for(int c1=h2*32;c1<h2*32+32;c1+=8){
        float4 q[6];
        const float4* r4=(const float4*)(wr+c1*3);
#pragma unroll
        for(int u=0;u<6;u++) q[u]=r4[u];
        const float* qq=(const float*)q;
#pragma unroll
        for(int u=0;u<8;u++){
          int c=c1+u;
          float T=S->sT[c], A0=S->s0[c], AL=S->sL[c];
          s += qq[u*3+0]*(T-AL) + qq[u*3+1]*T + qq[u*3+2]*(T-A0);
        }
      }
      S->part[tid]=s;
    } else if(tid>=384 && tid<392){
      int c2=tid-384;
      float s=0;
      for(int c1=0;c1<4;c1++){
        float T=S->totA_s[c1], A0=a0A[b*4+c1], AL=aLA[b*4+c1];
        const float* w=&tA_w2[(c2*4+c1)*3];
        s += w[0]*(T-AL) + w[1]*T + w[2]*(T-A0);
      }
      S->t1_s[c2]=s*invL;
    }
    __syncthreads();
    if(tid<128) S->te_s[tid]=(S->part[tid]+S->part[tid+128])*invL*scB;
    __syncthreads();
    // ---- GATE 1: iA producers only (12 fast blocks) ----
    if(tid==0){
      while(__hip_atomic_load(&cnt[1],__ATOMIC_ACQUIRE,__HIP_MEMORY_SCOPE_AGENT)<12)
        __builtin_amdgcn_s_sleep(8);
    }
    __syncthreads();
    if(tid<8) S->f1[tid]=S->t1_s[tid];
    else if(tid<16){
      int f=tid-8;
      float s=0;
#pragma unroll
      for(int g=0;g<24;g++) s+=i1part[(b*24+g)*8+f];
      S->f1[tid]=s;
    }
    __syncthreads();
    if(tid<64){
      float s=at_b1[lane];
#pragma unroll
      for(int i=0;i<16;i++) s+=S->f1[i]*at_w1[i*64+lane];
      float mu=wave_sum64(s)*(1.f/64.f);
      float d=s-mu;
      float var=wave_sum64(d*d)*(1.f/64.f);
      S->h[lane]=fmaxf(d*(1.0f/sqrtf(var+1e-5f))*at_ln_g[lane]+at_ln_b[lane],0.f);
    }
    __syncthreads();
    if(tid<256){
      int n=tid&127, h2=tid>>7;
      float a0=0,a1=0;
      for(int k=h2*32;k<h2*32+32;k+=2){
        a0+=S->h[k]*at_w2[k*128+n];
        a1+=S->h[k+1]*at_w2[(k+1)*128+n];
      }
      S->part[tid]=a0+a1;
    }
    __syncthreads();
    if(tid<128) S->tif[tid]=at_b2[tid]+S->part[tid]+S->part[tid+128];
    __syncthreads();
    if(tid<8){
      int f=tid;
      float ss=0; for(int e=0;e<16;e++){float v=S->tif[e*8+f]; ss+=v*v;}
      S->tden[f]=fmaxf(sqrtf(ss),1e-8f);
    } else if(tid<12){
      int t=tid-8;
      float ss=0; for(int e=0;e<16;e++){float v=protos[t*16+e]; ss+=v*v;}
      S->pden[t]=fmaxf(sqrtf(ss),1e-8f);
    }
    __syncthreads();
    if(tid<128) S->tifn[tid]=S->tif[tid]/S->tden[tid&7];
    if(tid<64) S->pn[tid]=protos[tid]/S->pden[tid>>4];
    __syncthreads();
    if(tid<32){
      int f=tid>>2, t=tid&3;
      float ss=0;
#pragma unroll
      for(int e=0;e<16;e++) ss+=S->pn[t*16+e]*S->tifn[e*8+f];
      float u=jax_uniform128(b*32+f*4+t);
      float g=-logf(-logf(u));
      S->z[tid]=ss+g;
    }
    __syncthreads();
    if(tid<8){
      float best=S->z[tid*4]; int bi=0;
      for(int t=1;t<4;t++){ float v=S->z[tid*4+t]; if(v>best){best=v;bi=t;} }
      S->sidx[tid]=bi;
    }
    __syncthreads();
    if(tid<4){
      int t=tid;
      int fi=0;
      for(int f=7;f>=0;f--) if(S->sidx[f]==t) fi=f;
      S->sfirst[t]=fi;
    } else if(tid<12){
      int f=tid-4;
      int c=0; for(int f2=0;f2<f;f2++) if(S->sidx[f2]==S->sidx[f]) c++;
      S->srank[f]=c;
    }
    __syncthreads();
    // ---- GATE 2: conv12 producers (96 blocks) ----
    if(tid==0){
      while(__hip_atomic_load(&cnt[0],__ATOMIC_ACQUIRE,__HIP_MEMORY_SCOPE_AGENT)<96)
        __builtin_amdgcn_s_sleep(8);
    }
    __syncthreads();
    if(tid<128) S->fbuf[tid]=S->te_s[tid];
    else if(tid<256){
      int c=tid-128;
      float s=0;
#pragma unroll 8
      for(int g=0;g<24;g++) s+=iepart[(b*24+g)*128+c];
      S->fbuf[tid]=s;
    }
    __syncthreads();
    if(tid<256){
      int l64=tid&63, q=tid>>6;
      float a0=0,a1=0,a2=0,a3=0;
      for(int k=q*64;k<q*64+64;k+=4){
        a0+=S->fbuf[k]  *bv_w1[k*64+l64];
        a1+=S->fbuf[k+1]*bv_w1[(k+1)*64+l64];
        a2+=S->fbuf[k+2]*bv_w1[(k+2)*64+l64];
        a3+=S->fbuf[k+3]*bv_w1[(k+3)*64+l64];
      }
      S->part[tid]=((a0+a1)+(a2+a3));
    }
    __syncthreads();
    if(tid<64){
      float s=bv_b1[lane]+S->part[lane]+S->part[64+lane]+S->part[128+lane]+S->part[192+lane];
      float mu=wave_sum64(s)*(1.f/64.f);
      float d=s-mu;
      float var=wave_sum64(d*d)*(1.f/64.f);
      S->hh[lane]=fmaxf(d*(1.0f/sqrtf(var+1e-5f))*bv_ln_g[lane]+bv_ln_b[lane],0.f);
    }
    __syncthreads();
    {
      int n=tid&255, h2=tid>>8;
      float a0=0,a1=0;
      for(int k=h2*32;k<h2*32+32;k+=2){
        a0+=S->hh[k]*bv_w2[k*256+n];
        a1+=S->hh[k+1]*bv_w2[(k+1)*256+n];
      }
      S->part[tid]=a0+a1;
    }
    __syncthreads();
    if(tid<256) S->ffn_s[tid]=bv_b2[tid]+S->part[tid]+S->part[tid+256];
    __syncthreads();
    if(tid<64){
      float sq=0;
#pragma unroll
      for(int u=0;u<4;u++){ float v=S->ffn_s[u*64+lane]; sq+=v*v; }
      sq=wave_sum64(sq);
      if(lane==0) S->finv_s=1.0f/fmaxf(sqrtf(sq),1e-12f);
    }
    __syncthreads();
    if(tid<256) S->ffn_s[tid]*=S->finv_s;
    __syncthreads();

    if(tid<128){
      int it=tid&63, h2=tid>>6;
      int t=it>>4, v=it&15;
      int tt=S->sidx[S->sfirst[t]];
      const float4* row=(const float4*)(bank+(tt*16+v)*256);
      float sa=0,na=0;
      for(int d4=h2*32;d4<h2*32+32;d4++){
        float4 r=row[d4];
        const float* fp=&S->ffn_s[d4*4];
        sa+=fp[0]*r.x+fp[1]*r.y+fp[2]*r.z+fp[3]*r.w;
        na+=r.x*r.x+r.y*r.y+r.z*r.z+r.w*r.w;
      }
      S->part[tid]=sa;
      S->part[256+tid]=na;
    }
    __syncthreads();
    if(tid<64) S->scores[tid]=(S->part[tid]+S->part[tid+64])/fmaxf(sqrtf(S->part[256+tid]+S->part[320+tid]),1e-12f);
    __syncthreads();
    if(tid<4){
      const float* sc=&S->scores[tid*16];
      unsigned used=0;
      for(int pk=0;pk<16;pk++){
        int best=-1; float bv=-1e30f;
        for(int v2=0;v2<16;v2++){
          if(used&(1u<<v2)) continue;
          float vv=sc[v2];
          if(best<0||vv>bv){bv=vv;best=v2;}
        }
        used|=1u<<best;
        S->order[tid*16+pk]=best;
      }
    }
    __syncthreads();
    if(tid<8){
      int t=S->sidx[tid];
      int v=S->order[t*16+S->srank[tid]];
      rowsp[b*8+tid]=t*16+v;
      idxo[b*8+tid]=t;
    }
    // mid ends here; hid1/hid3 computed in k_heads (parallelized 64-wide)
  }
}

// ---------------- k_heads: hid calc (0..63, ungated, release cnt[3])
//                  + A1 cols (64..79) + A3 cols (80..223), wcol prefetch before gate ----------------
__global__ __launch_bounds__(256) void k_heads(
    const float* __restrict__ bank, const int* __restrict__ rowsp,
    const float* __restrict__ m1_w1, const float* __restrict__ m1_b1,
    const float* __restrict__ m1_g,  const float* __restrict__ m1_bb,
    const float* __restrict__ m3_w1, const float* __restrict__ m3_b1,
    const float* __restrict__ m3_g,  const float* __restrict__ m3_bb,
    float* __restrict__ hid1, float* __restrict__ hid3,
    const float* __restrict__ w2a, const float* __restrict__ b2a,
    const float* __restrict__ w2b, const float* __restrict__ b2b,
    unsigned short* __restrict__ A1, unsigned short* __restrict__ A3,
    int* __restrict__ cnt){
  __shared__ float sm[2048];
  int tid=threadIdx.x;
  if(blockIdx.x<64){
    // ---- hid chunk: (br, m) GEMV + LN, parallel over 64 blocks ----
    float* row=sm;                       // 256 floats
    float (*red)[64]=(float(*)[64])(sm+256);  // 4x64
    int chunk=blockIdx.x;
    int m=chunk&1, br=chunk>>1;          // br = b*8+r in [0,32)
    int lane=tid&63, q=tid>>6;
    if(tid<64){
      float4 v=((const float4*)(bank+(size_t)rowsp[br]*256))[tid];
      ((float4*)row)[tid]=v;
    }
    __syncthreads();
    const float* w=m?m3_w1:m1_w1;
    float a0=0,a1=0,a2=0,a3=0;
    for(int d=q*64;d<q*64+64;d+=4){
      a0+=row[d]  *w[(size_t)d*64+lane];
      a1+=row[d+1]*w[(size_t)(d+1)*64+lane];
      a2+=row[d+2]*w[(size_t)(d+2)*64+lane];
      a3+=row[d+3]*w[(size_t)(d+3)*64+lane];
    }
    red[q][lane]=((a0+a1)+(a2+a3));
    __syncthreads();
    if(tid<64){
      const float* b1=m?m3_b1:m1_b1;
      const float* g =m?m3_g :m1_g;
      const float* bb=m?m3_bb:m1_bb;
      float s=b1[lane]+red[0][lane]+red[1][lane]+red[2][lane]+red[3][lane];
      float mu=wave_sum64(s)*(1.f/64.f);
      float d=s-mu;
      float var=wave_sum64(d*d)*(1.f/64.f);
      float* hid=m?hid3:hid1;
      hid[br*64+lane]=fmaxf(d*(1.0f/sqrtf(var+1e-5f))*g[lane]+bb[lane],0.f);
    }
    __syncthreads();   // stores drained before release
    if(tid==0) __hip_atomic_fetch_add(&cnt[3],1,__ATOMIC_RELEASE,__HIP_MEMORY_SCOPE_AGENT);
  } else if(blockIdx.x<80){
    int n=(blockIdx.x-64)*256+tid;
    float wcol[64];
#pragma unroll
    for(int k=0;k<64;k++) wcol[k]=w2a[k*4096+n];
    float bb=b2a[n];
    if(tid==0){
      while(__hip_atomic_load(&cnt[3],__ATOMIC_ACQUIRE,__HIP_MEMORY_SCOPE_AGENT)<64)
        __builtin_amdgcn_s_sleep(8);
    }
    __syncthreads();
    for(int i=tid;i<2048;i+=256) sm[i]=hid1[i];
    __syncthreads();
    for(int bf=0;bf<32;bf++){
      float s=bb;
#pragma unroll
      for(int k=0;k<64;k++) s+=sm[bf*64+k]*wcol[k];
      A1[bf*4096+n]=f2bf(s);
    }
  } else {
    int n=(blockIdx.x-80)*256+tid;
    float wcol[64];
#pragma unroll
    for(int k=0;k<64;k++) wcol[k]=w2b[(size_t)k*36864+n];
    float bb=b2b[n];
    if(tid==0){
      while(__hip_atomic_load(&cnt[3],__ATOMIC_ACQUIRE,__HIP_MEMORY_SCOPE_AGENT)<64)
        __builtin_amdgcn_s_sleep(8);
    }
    __syncthreads();
    for(int i=tid;i<2048;i+=256) sm[i]=hid3[i];
    __syncthreads();
    int o=n/576, rem=n-o*576;
    int c=rem/9, tap=rem-c*9;
    size_t base=((size_t)tap*64+o)*64+c;
    for(int bf=0;bf<32;bf++){
      float s=bb;
#pragma unroll
      for(int k=0;k<64;k++) s+=sm[bf*64+k]*wcol[k];
      A3[(size_t)bf*9*4096+base]=f2bf(s);
    }
  }
}

// ---------------- fused dynamic conv: LDS-staged image slab, 512 thr, f-halves, zc+residual ----------------
__global__ __launch_bounds__(512) void k_dynF(const unsigned short* __restrict__ imgTP,
                       const unsigned short* __restrict__ A1, const unsigned short* __restrict__ A3,
                       const int* __restrict__ idx, const float* __restrict__ bn,
                       const float* __restrict__ zc_w, const float* __restrict__ zc_b,
                       const float* __restrict__ img, float* __restrict__ out){
  int blk=blockIdx.x;
  int b=blk/48, r0=blk-b*48;
  int tid=threadIdx.x;
  int lane=tid&63, w8=tid>>6;
  int mt=w8&3, fh=w8>>2;
  int n0=lane&15, kg=lane>>4;
  __shared__ unsigned short slab[7*54*SLABP];
  __shared__ float xl[64*50];
  __shared__ float zl[4096];
  // hoisted: idx + bn params issued before staging so the tt-branch doesn't stall post-barrier
  int tts[4];
#pragma unroll
  for(int i=0;i<4;i++) tts[i]=idx[b*8+fh*4+i];
  int obase=mt*16+kg*4;
  float scale[4],m_[4],be_[4];
#pragma unroll
  for(int reg=0;reg<4;reg++){
    int o=obase+reg;
    scale[reg]=bn[o]/sqrtf(bn[192+o]+1e-5f);
    m_[reg]=bn[128+o]; be_[reg]=bn[64+o];
  }
  for(int i=tid;i<4096;i+=512) zl[i]=zc_w[i];
  for(int i=tid;i<3200;i+=512) xl[i]=0.f;
  {
    const unsigned short* ibase=imgTP+((size_t)b*PHW+(size_t)r0*PP)*64;
    for(int e=tid;e<7*54*8;e+=512){
      int rr=e/(54*8), rem=e-rr*54*8, w=rem>>3, ck=rem&7;
      uint4 v=*(const uint4*)(ibase + ((size_t)(rr*PP+w))*64 + ck*8);
      *(uint4*)(slab + (rr*54+w)*SLABP + ck*8)=v;
    }
  }
  __syncthreads();
  float xsum[3][4];
#pragma unroll
  for(int wc=0;wc<3;wc++)
#pragma unroll
    for(int reg=0;reg<4;reg++) xsum[wc][reg]=0.f;
#pragma unroll
  for(int fi=0;fi<4;fi++){
    int f=fh*4+fi;
    int bf=b*8+f;
    int tt=tts[fi];
    floatx4 acc[3];
#pragma unroll
    for(int i=0;i<3;i++) acc[i]=(floatx4){0.f,0.f,0.f,0.f};
    if(tt==0){
      const unsigned short* Ab=A1+(size_t)bf*4096;
#pragma unroll
      for(int c0=0;c0<64;c0+=32){
        short8 a=*(const short8*)(Ab+((mt*16+n0)*64+c0+kg*8));
#pragma unroll
        for(int wc=0;wc<3;wc++){
          short8 bv=*(const short8*)(slab + (3*54 + wc*16+n0+3)*SLABP + c0+kg*8);
          acc[wc]=__builtin_amdgcn_mfma_f32_16x16x32_bf16(a,bv,acc[wc],0,0,0);
        }
      }
    } else {
      int d=tt;
      const unsigned short* A3b=A3+(size_t)bf*9*4096;
#pragma unroll
      for(int ti=0;ti<3;ti++){
        int lr=d*(ti-1)+3;
#pragma unroll
        for(int tj=0;tj<3;tj++){
          int tap=ti*3+tj;
          int dw=d*(tj-1)+3;
          const unsigned short* Ab=A3b+(size_t)tap*4096;
#pragma unroll
          for(int c0=0;c0<64;c0+=32){
            short8 a=*(const short8*)(Ab+((mt*16+n0)*64+c0+kg*8));
#pragma unroll
            for(int wc=0;wc<3;wc++){
              short8 bv=*(const short8*)(slab + (lr*54 + wc*16+n0+dw)*SLABP + c0+kg*8);
              acc[wc]=__builtin_amdgcn_mfma_f32_16x16x32_bf16(a,bv,acc[wc],0,0,0);
            }
          }
        }
      }
    }
#pragma unroll
    for(int wc=0;wc<3;wc++)
#pragma unroll
      for(int reg=0;reg<4;reg++)
        xsum[wc][reg]+=leaky((acc[wc][reg]-m_[reg])*scale[reg]+be_[reg]);
  }
#pragma unroll
  for(int wc=0;wc<3;wc++)
#pragma unroll
    for(int reg=0;reg<4;reg++)
      atomicAdd(&xl[(obase+reg)*50 + wc*16+n0], xsum[wc][reg]*0.125f);
  __syncthreads();
  size_t base=(size_t)b*64*HW + r0*48;
  for(int e=tid;e<3072;e+=512){
    int o=e/48, px=e-o*48;
    float s=zc_b[o];
#pragma unroll
    for(int c=0;c<64;c++) s+=zl[o*64+c]*xl[c*50+px];
    size_t a=base+(size_t)o*HW+px;
    out[a]=s+img[a];
  }
}

extern "C" void kernel_launch(void* const* d_in, const int* in_sizes, int n_in,
                              void* d_out, int out_size, void* d_ws, size_t ws_size,
                              hipStream_t stream){
  const float* bank   =(const float*)d_in[0];
  const float* task_f =(const float*)d_in[1];
  const float* img_f  =(const float*)d_in[2];
  const float* protos =(const float*)d_in[3];
  const float* tA_w1  =(const float*)d_in[4];
  const float* tA_w2  =(const float*)d_in[5];
  const float* iA_w   =(const float*)d_in[6];
  const float* iA_bn  =(const float*)d_in[7];
  const float* at_w1  =(const float*)d_in[8];
  const float* at_b1  =(const float*)d_in[9];
  const float* at_ln_g=(const float*)d_in[10];
  const float* at_ln_b=(const float*)d_in[11];
  const float* at_w2  =(const float*)d_in[12];
  const float* at_b2  =(const float*)d_in[13];
  const float* bv_t1  =(const float*)d_in[14];
  const float* bv_t2  =(const float*)d_in[15];
  const float* bv_ic1 =(const float*)d_in[16];
  const float* bv_bn1 =(const float*)d_in[17];
  const float* bv_ic2 =(const float*)d_in[18];
  const float* bv_bn2 =(const float*)d_in[19];
  const float* bv_w1  =(const float*)d_in[20];
  const float* bv_b1  =(const float*)d_in[21];
  const float* bv_ln_g=(const float*)d_in[22];
  const float* bv_ln_b=(const float*)d_in[23];
  const float* bv_w2  =(const float*)d_in[24];
  const float* bv_b2  =(const float*)d_in[25];
  const float* m1_w1  =(const float*)d_in[26];
  const float* m1_b1  =(const float*)d_in[27];
  const float* m1_ln_g=(const float*)d_in[28];
  const float* m1_ln_b=(const float*)d_in[29];
  const float* m1_w2  =(const float*)d_in[30];
  const float* m1_b2  =(const float*)d_in[31];
  const float* m3_w1  =(const float*)d_in[32];
  const float* m3_b1  =(const float*)d_in[33];
  const float* m3_ln_g=(const float*)d_in[34];
  const float* m3_ln_b=(const float*)d_in[35];
  const float* m3_w2  =(const float*)d_in[36];
  const float* m3_b2  =(const float*)d_in[37];
  const float* blr_bn =(const float*)d_in[38];
  const float* zc_w   =(const float*)d_in[39];
  const float* zc_b   =(const float*)d_in[40];

  float* ws=(float*)d_ws;
  // all accumulators are per-block partial slots -> no zero-init needed anywhere
  float* totApart=ws+0;        // 4*64*4            [0,1024)
  float* a0A  =ws+1024;        // 16
  float* aLA  =ws+1040;        // 16
  float* totBpart=ws+1056;     // 4*64*64           [1056,17440)
  float* a0B  =ws+17440;       // 256
  float* aLB  =ws+17696;       // 256
  float* rmspart=ws+17952;     // 256
  float* i1part =ws+18208;     // 4*24*8 = 768
  float* iepart =ws+18976;     // 4*24*128 = 12288  [18976,31264)
  int*   idxp   =(int*)(ws+31264);                  // 32
  int*   rowsp  =(int*)(ws+31296);                  // 32
  float* hid1=ws+31328;        // 2048
  float* hid3=ws+33376;        // 2048 -> ends 35424
  unsigned short* A1p  =(unsigned short*)(ws+35424);     // 131072 bf16  -> ends 100960
  unsigned short* A3p  =(unsigned short*)(ws+100960);    // 1179648 bf16 -> ends 690784
  unsigned short* imgTP=(unsigned short*)(ws+690784);    // 746496 bf16 (padded) -> ends 1064032
  unsigned short* W1Tp =(unsigned short*)(ws+1064032);   // 36864 bf16 -> ends 1082464
  unsigned short* W2Tp =(unsigned short*)(ws+1082464);   // 73728 bf16 -> ends 1119328
  unsigned short* WATp =(unsigned short*)(ws+1119328);   // 9216 bf16 -> ends 1123936
  float* warm =ws+1123936;                               // 1024 f dummy sink
  int*   cnt  =(int*)(ws+1124960);                       // 4 ints, zeroed by k_pre
  // total ~4.5 MB

  k_pre<<<948,256,0,stream>>>(task_f, tA_w1, bv_t1,
                              totApart, a0A, aLA, totBpart, a0B, aLB, rmspart,
                              img_f, bv_ic1, bv_ic2, iA_w, imgTP, W1Tp, W2Tp, WATp,
                              m1_w1, m3_w1, bv_w1, bv_w2, bv_t2, at_w2, bank,
                              m1_w2, m3_w2, zc_w, warm, cnt);
  k_cm<<<112,512,0,stream>>>(imgTP, W1Tp, W2Tp, WATp, bv_bn1, bv_bn2, iA_bn,
                             iepart, i1part,
                             totApart, a0A, aLA, totBpart, a0B, aLB, rmspart,
                             tA_w2, bv_t2,
                             at_w1, at_b1, at_ln_g, at_ln_b, at_w2, at_b2, protos,
                             bv_w1, bv_b1, bv_ln_g, bv_ln_b, bv_w2, bv_b2, bank,
                             idxp, rowsp, cnt);
  k_heads<<<224,256,0,stream>>>(bank, rowsp,
                                m1_w1, m1_b1, m1_ln_g, m1_ln_b,
                                m3_w1, m3_b1, m3_ln_g, m3_ln_b,
                                hid1, hid3,
                                m1_w2, m1_b2, m3_w2, m3_b2, A1p, A3p, cnt);
  k_dynF<<<192,512,0,stream>>>(imgTP, A1p, A3p, idxp, blr_bn, zc_w, zc_b, img_f, (float*)d_out);

  (void)in_sizes; (void)n_in; (void)out_size; (void)ws_size;
}

// Round 11
// 261.849 us; speedup vs baseline: 1.0281x; 1.0281x over previous
//
#include <hip/hip_runtime.h>
#include <math.h>

#define LEAKC 0.2f

#define NB 4
#define NC 64
#define LLEN 16384
#define HW 2304
#define PP 54          // padded pitch (48 + 2*3)
#define PHW 2916       // 54*54
#define SLABP 72       // slab c-pitch: 2-way max conflicts (free per m136)
#define CP 72          // ie1 LDS c-pitch
#define IE1C 50        // ie1 LDS cols (padded img cols 2..51)

typedef __attribute__((ext_vector_type(8))) short short8;
typedef __attribute__((ext_vector_type(4))) float floatx4;

__device__ __forceinline__ float leaky(float x){ return x > 0.f ? x : LEAKC*x; }

__device__ __forceinline__ float wave_sum64(float v){
  for(int off=32;off;off>>=1) v += __shfl_xor(v,off);
  return v;
}

__device__ __forceinline__ unsigned short f2bf(float x){
  unsigned u=__float_as_uint(x);
  unsigned r=u+0x7FFFu+((u>>16)&1u);
  return (unsigned short)(r>>16);
}

__device__ __forceinline__ void threefry2x32(unsigned k0, unsigned k1, unsigned& x0, unsigned& x1){
  unsigned ks0=k0, ks1=k1, ks2=k0^k1^0x1BD11BDAu;
  x0+=ks0; x1+=ks1;
  const int rot0[4]={13,15,26,6};
  const int rot1[4]={17,29,16,24};
#define TF_APPLY(rr) {for(int r=0;r<4;r++){x0+=x1; x1=(x1<<rr[r])|(x1>>(32-rr[r])); x1^=x0;}}
  TF_APPLY(rot0); x0+=ks1; x1+=ks2+1u;
  TF_APPLY(rot1); x0+=ks2; x1+=ks0+2u;
  TF_APPLY(rot0); x0+=ks0; x1+=ks1+3u;
  TF_APPLY(rot1); x0+=ks1; x1+=ks2+4u;
  TF_APPLY(rot0); x0+=ks2; x1+=ks0+5u;
#undef TF_APPLY
}

__device__ __forceinline__ float jax_uniform128(int i){
  unsigned x0=0u, x1=(unsigned)i;
  threefry2x32(0u,42u,x0,x1);
  unsigned bits = x0 ^ x1;
  unsigned fb=(bits>>9)|0x3f800000u;
  float f=__uint_as_float(fb)-1.0f;
  float u=f*(1.0f-1e-10f)+1e-10f;
  return fmaxf(1e-10f,u);
}

struct MidSM {
  float sT[64], s0[64], sL[64];
  float red8[64][9];
  float totA_s[4]; float rms_s;
  float part[512];
  float te_s[128], t1_s[8];
  float f1[16], h[64], tif[128], tifn[128], tden[8], pden[4], pn[64], z[32];
  int sidx[8], sfirst[4], srank[8], rows[8];
  float fbuf[256], hh[64], ffn_s[256], finv_s;
  float scores[64];
  int order[64];
  float bvf[2048];
};

// ---------------- k_pre: stats partials (0..255) + padded imgT (256..399) + weight prep (400..867)
//                  + L3 warm (868..931) + imgTP halo zero + counter zero (932..947) ----------------
__global__ __launch_bounds__(256) void k_pre(const float* __restrict__ task_f,
                      const float* __restrict__ w1A, const float* __restrict__ w1B,
                      float* __restrict__ totApart, float* __restrict__ a0A, float* __restrict__ aLA,
                      float* __restrict__ totBpart, float* __restrict__ a0B, float* __restrict__ aLB,
                      float* __restrict__ rmspart,
                      const float* __restrict__ img,
                      const float* __restrict__ w1, const float* __restrict__ w2,
                      const float* __restrict__ wa,
                      unsigned short* __restrict__ imgTP,
                      unsigned short* __restrict__ W1T, unsigned short* __restrict__ W2T,
                      unsigned short* __restrict__ WAT,
                      const float* __restrict__ mw1, const float* __restrict__ mw3,
                      const float* __restrict__ bvw1p, const float* __restrict__ bvw2p,
                      const float* __restrict__ bvt2p, const float* __restrict__ atw2p,
                      const float* __restrict__ bankp,
                      const float* __restrict__ m1w2p, const float* __restrict__ m3w2p,
                      const float* __restrict__ zcwp,
                      float* __restrict__ warm, int* __restrict__ cnt){
  if(blockIdx.x<256){
    int b=blockIdx.x>>6, seg=blockIdx.x&63;
    const float* x=task_f+b*LLEN;
    float tA[4]={0,0,0,0};
    float tB[64];
#pragma unroll
    for(int c=0;c<64;c++) tB[c]=0.f;
    float sq=0.f;
    int l=seg*256+threadIdx.x;
    {
      float xm=(l>0)?x[l-1]:0.f;
      float xc=x[l];
      float xp=(l<LLEN-1)?x[l+1]:0.f;
      sq=xc*xc;
#pragma unroll
      for(int c=0;c<4;c++){
        float a=leaky(w1A[c*3+0]*xm + w1A[c*3+1]*xc + w1A[c*3+2]*xp);
        tA[c]=a;
        if(l==0) a0A[b*4+c]=a;
        if(l==LLEN-1) aLA[b*4+c]=a;
      }
#pragma unroll
      for(int c=0;c<64;c++){
        float a=leaky(w1B[c*3+0]*xm + w1B[c*3+1]*xc + w1B[c*3+2]*xp);
        tB[c]=a;
        if(l==0) a0B[b*64+c]=a;
        if(l==LLEN-1) aLB[b*64+c]=a;
      }
    }
    sq=wave_sum64(sq);
#pragma unroll
    for(int c=0;c<4;c++) tA[c]=wave_sum64(tA[c]);
#pragma unroll
    for(int c=0;c<64;c++){
      float v=tB[c];
      for(int off=32;off;off>>=1) v+=__shfl_down(v,off);
      tB[c]=v;
    }
    __shared__ float redB[4][64];
    __shared__ float redA[4][4];
    __shared__ float redQ[4];
    int wave=threadIdx.x>>6, lane=threadIdx.x&63;
    if(lane==0){
#pragma unroll
      for(int c=0;c<64;c++) redB[wave][c]=tB[c];
#pragma unroll
      for(int c=0;c<4;c++) redA[wave][c]=tA[c];
      redQ[wave]=sq;
    }
    __syncthreads();
    if(threadIdx.x<64){
      float s=redB[0][threadIdx.x]+redB[1][threadIdx.x]+redB[2][threadIdx.x]+redB[3][threadIdx.x];
      totBpart[(size_t)(b*64+seg)*64+threadIdx.x]=s;
    } else if(threadIdx.x<68){
      int c=threadIdx.x-64;
      totApart[(b*64+seg)*4+c]=redA[0][c]+redA[1][c]+redA[2][c]+redA[3][c];
    } else if(threadIdx.x==68){
      rmspart[b*64+seg]=redQ[0]+redQ[1]+redQ[2]+redQ[3];
    }
  } else if(blockIdx.x<400){
    int blk=blockIdx.x-256;
    int b=blk/36, t=blk%36;
    int p0=t*64;
    __shared__ float tile[64][65];
    int pp=threadIdx.x&63, c4=threadIdx.x>>6;
    for(int r=0;r<16;r++){
      int c=c4*16+r;
      tile[c][pp]=img[(b*64+c)*HW + p0+pp];
    }
    __syncthreads();
    int pxl=threadIdx.x>>2, cg=(threadIdx.x&3)*16;
    unsigned out[8];
#pragma unroll
    for(int q=0;q<8;q++){
      unsigned lo=f2bf(tile[cg+2*q][pxl]);
      unsigned hi=f2bf(tile[cg+2*q+1][pxl]);
      out[q]=lo|(hi<<16);
    }
    int px=p0+pxl;
    int h=px/48, w=px-h*48;
    int poff=(h+3)*PP+(w+3);
    unsigned* dst=(unsigned*)(imgTP + ((size_t)(b*PHW+poff))*64 + cg);
#pragma unroll
    for(int q=0;q<8;q++) dst[q]=out[q];
  } else if(blockIdx.x<868){
    int n=(blockIdx.x-400)*256+threadIdx.x;
    if(n<9*64*64){
      int tap=n>>12, oc=(n>>6)&63, c=n&63;
      W1T[n]=f2bf(w1[oc*576+c*9+tap]);
    } else if(n<9*64*64+9*128*64){
      int m=n-9*64*64;
      int tap=m/8192, r=m-tap*8192, oc=r>>6, c=r&63;
      W2T[m]=f2bf(w2[oc*576+c*9+tap]);
    } else {
      int q=n-9*64*64-9*128*64;
      if(q<9*16*64){
        int tap=q>>10, r=q&1023, o=r>>6, c=r&63;
        WAT[q]=(o<8)?f2bf(wa[o*576+c*9+tap]):(unsigned short)0;
      }
    }
  } else if(blockIdx.x<932){
    // ---- L3 warm (64 blocks = 16384 threads): later-kernel weights -> L3 ----
    int t=(blockIdx.x-868)*256+threadIdx.x;
    float a=0.f;
    for(int i=t;i*16<16384;i+=16384) a+=mw1[i*16];
    for(int i=t;i*16<16384;i+=16384) a+=mw3[i*16];
    for(int i=t;i*16<16384;i+=16384) a+=bvw1p[i*16];
    for(int i=t;i*16<16384;i+=16384) a+=bvw2p[i*16];
    for(int i=t;i*16<24576;i+=16384) a+=bvt2p[i*16];
    for(int i=t;i*16<8192;i+=16384) a+=atw2p[i*16];
    for(int i=t;i*16<16384;i+=16384) a+=bankp[i*16];
    for(int i=t;i*16<262144;i+=16384) a+=m1w2p[i*16];
    for(int i=t;i*16<2359296;i+=16384) a+=m3w2p[i*16];
    for(int i=t;i*16<4096;i+=16384) a+=zcwp[i*16];
    warm[t&1023]=a;
  } else {
    // imgTP halo zero: 612 halo px per b, 8 x uint4 chunks per px (+ counter zero)
    if(blockIdx.x==932 && threadIdx.x<4)
      __hip_atomic_store(&cnt[threadIdx.x],0,__ATOMIC_RELAXED,__HIP_MEMORY_SCOPE_AGENT);
    int id=(blockIdx.x-932)*256+threadIdx.x;   // 4096 threads
    uint4 z=make_uint4(0,0,0,0);
    for(int cch=id;cch<19584;cch+=4096){
      int ck=cch&7, pxid=cch>>3;               // pxid 0..2447
      int b=pxid/612, p=pxid-b*612;
      int h,w;
      if(p<324){ int r=p/54; w=p-r*54; h=(r<3)?r:(r+48); }
      else { int q=p-324; int r2=q/6; int cc=q-r2*6; h=3+r2; w=(cc<3)?cc:(cc+48); }
      *(uint4*)(imgTP + ((size_t)(b*PHW + h*PP + w))*64 + ck*8)=z;
    }
  }
}

// =========== k_cm: conv12 (0..95) + iA (96..107) -> release cnt[0]; mid (108..111) gated at 108 ===========
__global__ __launch_bounds__(512) void k_cm(const unsigned short* __restrict__ imgTP,
    const unsigned short* __restrict__ W1T, const unsigned short* __restrict__ W2T,
    const unsigned short* __restrict__ WAT,
    const float* __restrict__ bn1, const float* __restrict__ bn2, const float* __restrict__ bnA,
    float* __restrict__ iepart, float* __restrict__ i1part,
    const float* __restrict__ totApart, const float* __restrict__ a0A, const float* __restrict__ aLA,
    const float* __restrict__ totBpart, const float* __restrict__ a0B, const float* __restrict__ aLB,
    const float* __restrict__ rmspart,
    const float* __restrict__ tA_w2, const float* __restrict__ bv_t2,
    const float* __restrict__ at_w1, const float* __restrict__ at_b1,
    const float* __restrict__ at_ln_g, const float* __restrict__ at_ln_b,
    const float* __restrict__ at_w2, const float* __restrict__ at_b2,
    const float* __restrict__ protos,
    const float* __restrict__ bv_w1, const float* __restrict__ bv_b1,
    const float* __restrict__ bv_ln_g, const float* __restrict__ bv_ln_b,
    const float* __restrict__ bv_w2, const float* __restrict__ bv_b2,
    const float* __restrict__ bank,
    const float* __restrict__ m1_w1, const float* __restrict__ m1_b1,
    const float* __restrict__ m1_g,  const float* __restrict__ m1_bb,
    const float* __restrict__ m3_w1, const float* __restrict__ m3_b1,
    const float* __restrict__ m3_g,  const float* __restrict__ m3_bb,
    int* __restrict__ idxo, float* __restrict__ hid1, float* __restrict__ hid3,
    int* __restrict__ cnt){
  __shared__ __align__(16) char smraw[75456];
  int tid=threadIdx.x;
  int lane=tid&63, wv=tid>>6;
  int n0=lane&15, kg=lane>>4;
  if(blockIdx.x<96){
    int blk=blockIdx.x;
    int b=blk/24, hp=blk-b*24;
    int h0=hp*2;
    unsigned short* slab=(unsigned short*)smraw;          // 6*54*SLABP shorts = 46656B
    unsigned short* ie1=(unsigned short*)(smraw+46656);   // 4*IE1C*CP shorts = 28800B
    {
      const unsigned short* ibase=imgTP+((size_t)b*PHW+(size_t)(h0+1)*PP)*64;
      for(int e=tid;e<6*54*8;e+=512){
        int rr=e/(54*8), rem=e-rr*54*8, w=rem>>3, ck=rem&7;
        uint4 v=*(const uint4*)(ibase+((size_t)(rr*PP+w))*64+ck*8);
        *(uint4*)(slab+(rr*54+w)*SLABP+ck*8)=v;
      }
      if(tid<64){  // zero-pad ie1 cols q=0 and q=49
        int br=tid>>4, cq=(tid>>3)&1, ck=tid&7;
        *(uint4*)(ie1+((size_t)(br*IE1C+(cq?49:0)))*CP+ck*8)=make_uint4(0,0,0,0);
      }
    }
    __syncthreads();
    // phase 1: conv1 (M=64 oc) -> ie1
    {
      int mt=wv&3, rh=wv>>2;
      floatx4 acc[2][3];
#pragma unroll
      for(int rr=0;rr<2;rr++)
#pragma unroll
        for(int nt=0;nt<3;nt++) acc[rr][nt]=(floatx4){0.f,0.f,0.f,0.f};
#pragma unroll
      for(int ti=0;ti<3;ti++){
#pragma unroll
        for(int tj=0;tj<3;tj++){
          int tap=ti*3+tj;
          const unsigned short* Ab=W1T+(size_t)tap*4096;
#pragma unroll
          for(int c0=0;c0<64;c0+=32){
            short8 a=*(const short8*)(Ab+((mt*16+n0)*64+c0+kg*8));
#pragma unroll
            for(int rr=0;rr<2;rr++){
              int sr=rh*2+rr+ti;
#pragma unroll
              for(int nt=0;nt<3;nt++){
                int sc=nt*16+n0+tj+2;
                short8 bv=*(const short8*)(slab+(sr*54+sc)*SLABP+c0+kg*8);
                acc[rr][nt]=__builtin_amdgcn_mfma_f32_16x16x32_bf16(a,bv,acc[rr][nt],0,0,0);
              }
            }
          }
        }
      }
      int obase=mt*16+kg*4;
      float scale[4],m_[4],be_[4];
#pragma unroll
      for(int reg=0;reg<4;reg++){
        int o=obase+reg;
        scale[reg]=bn1[o]/sqrtf(bn1[192+o]+1e-5f);
        m_[reg]=bn1[128+o]; be_[reg]=bn1[64+o];
      }
#pragma unroll
      for(int rr=0;rr<2;rr++){
        int br=rh*2+rr;
        bool rv=((unsigned)(h0-1+br))<48u;
#pragma unroll
        for(int nt=0;nt<3;nt++){
          float v0=rv?leaky((acc[rr][nt][0]-m_[0])*scale[0]+be_[0]):0.f;
          float v1=rv?leaky((acc[rr][nt][1]-m_[1])*scale[1]+be_[1]):0.f;
          float v2=rv?leaky((acc[rr][nt][2]-m_[2])*scale[2]+be_[2]):0.f;
          float v3=rv?leaky((acc[rr][nt][3]-m_[3])*scale[3]+be_[3]):0.f;
          unsigned w0=f2bf(v0)|((unsigned)f2bf(v1)<<16);
          unsigned w1=f2bf(v2)|((unsigned)f2bf(v3)<<16);
          uint2 pk={w0,w1};
          *(uint2*)(ie1+((size_t)(br*IE1C+(nt*16+1+n0)))*CP+obase)=pk;
        }
      }
    }
    __syncthreads();
    // phase 2: conv2 (M=128 oc) -> mean partial
    {
      int mt2=wv;
      floatx4 acc[6];
#pragma unroll
      for(int i=0;i<6;i++) acc[i]=(floatx4){0.f,0.f,0.f,0.f};
#pragma unroll
      for(int ti=0;ti<3;ti++){
#pragma unroll
        for(int tj=0;tj<3;tj++){
          int tap=ti*3+tj;
          const unsigned short* Ab=W2T+(size_t)tap*8192;
#pragma unroll
          for(int c0=0;c0<64;c0+=32){
            short8 a=*(const short8*)(Ab+((mt2*16+n0)*64+c0+kg*8));
#pragma unroll
            for(int rr=0;rr<2;rr++){
              int sr=rr+ti;
#pragma unroll
              for(int wc=0;wc<3;wc++){
                int q=wc*16+n0+tj;
                short8 bv=*(const short8*)(ie1+((size_t)(sr*IE1C+q))*CP+c0+kg*8);
                acc[rr*3+wc]=__builtin_amdgcn_mfma_f32_16x16x32_bf16(a,bv,acc[rr*3+wc],0,0,0);
              }
            }
          }
        }
      }
      int obase=mt2*16+kg*4;
#pragma unroll
      for(int reg=0;reg<4;reg++){
        int o=obase+reg;
        float scale=bn2[o]/sqrtf(bn2[384+o]+1e-5f);
        float m_=bn2[256+o], be_=bn2[128+o];
        float part=0;
#pragma unroll
        for(int i=0;i<6;i++) part+=leaky((acc[i][reg]-m_)*scale+be_);
        for(int off=1;off<16;off<<=1) part+=__shfl_xor(part,off);
        if(n0==0) iepart[(b*24+hp)*128+o]=part*(1.f/2304.f);
      }
    }
    __syncthreads();   // all stores drained (vmcnt before barrier)
    if(tid==0) __hip_atomic_fetch_add(&cnt[0],1,__ATOMIC_RELEASE,__HIP_MEMORY_SCOPE_AGENT);
  } else if(blockIdx.x<108){
    // iA branch: 12 blocks x 8 waves; wave handles one hp
    int blk2=blockIdx.x-96;
    int b=blk2/3, hg=blk2%3;
    int hp=hg*8+wv;
    int h0=hp*2;
    const unsigned short* ib=imgTP+(size_t)b*PHW*64;
    floatx4 acc[6];
#pragma unroll
    for(int i=0;i<6;i++) acc[i]=(floatx4){0.f,0.f,0.f,0.f};
#pragma unroll
    for(int ti=0;ti<3;ti++){
#pragma unroll
      for(int tj=0;tj<3;tj++){
        int tap=ti*3+tj;
        const unsigned short* Ab=WAT+(size_t)tap*1024;
#pragma unroll
        for(int c0=0;c0<64;c0+=32){
          short8 a=*(const short8*)(Ab+(n0*64+c0+kg*8));
#pragma unroll
          for(int rr=0;rr<2;rr++){
            int r=h0+rr+ti-1+3;
#pragma unroll
            for(int wc=0;wc<3;wc++){
              int w=wc*16+n0+tj-1+3;
              short8 bv=*(const short8*)(ib+((size_t)(r*PP+w)*64+c0+kg*8));
              acc[rr*3+wc]=__builtin_amdgcn_mfma_f32_16x16x32_bf16(a,bv,acc[rr*3+wc],0,0,0);
            }
          }
        }
      }
    }
    int obase=kg*4;
#pragma unroll
    for(int reg=0;reg<4;reg++){
      int o=obase+reg;
      float part=0;
      if(o<8){
        float scale=bnA[o]/sqrtf(bnA[24+o]+1e-5f);
        float m_=bnA[16+o], be_=bnA[8+o];
#pragma unroll
        for(int i=0;i<6;i++) part+=leaky((acc[i][reg]-m_)*scale+be_);
      }
      for(int off=1;off<16;off<<=1) part+=__shfl_xor(part,off);
      if(n0==0 && o<8) i1part[(b*24+hp)*8+o]=part*(1.f/2304.f);
    }
    __syncthreads();
    if(tid==0) __hip_atomic_fetch_add(&cnt[0],1,__ATOMIC_RELEASE,__HIP_MEMORY_SCOPE_AGENT);
  } else {
    // =================== MID (overlapped; gated before i1/ie consumption) ===================
    MidSM* S=(MidSM*)smraw;
    int b=blockIdx.x-108;
    const float invL=1.0f/16384.0f;
    // entry: k_pre-derived reductions only (safe pre-gate)
    {
      int c8=tid>>3, g8=tid&7;
      float s8=0;
#pragma unroll
      for(int seg=g8*8;seg<g8*8+8;seg++) s8+=totBpart[(size_t)(b*64+seg)*64+c8];
      S->red8[c8][g8]=s8;
    }
    if(tid>=64 && tid<128){
      int t=tid-64;
      S->s0[t]=a0B[b*64+t]; S->sL[t]=aLB[b*64+t];
    } else if(tid>=128 && tid<192){
      float v=rmspart[b*64+(tid-128)];
      v=wave_sum64(v);
      if(tid==128) S->rms_s=v;
    } else if(tid>=192 && tid<196){
      int c=tid-192;
      float s=0;
#pragma unroll 8
      for(int seg=0;seg<64;seg++) s+=totApart[(b*64+seg)*4+c];
      S->totA_s[c]=s;
    }
    __syncthreads();
    if(tid<64){
      float s=0;
#pragma unroll
      for(int g=0;g<8;g++) s+=S->red8[tid][g];
      S->sT[tid]=s;
    }
    __syncthreads();
    float scB=1.0f/(sqrtf(S->rms_s*invL)+1e-8f);
    if(tid<256){
      int c2=tid&127, h2=tid>>7;
      const float* wr=bv_t2+c2*192;
      float s=0;
      for(int c1=h2*32;c1<h2*32+32;c1+=8){
        float4 q[6];
        const float4* r4=(const float4*)(wr+c1*3);
#pragma unroll
        for(int u=0;u<6;u++) q[u]=r4[u];
        const float* qq=(const float*)q;
#pragma unroll
        for(int u=0;u<8;u++){
          int c=c1+u;
          float T=S->sT[c], A0=S->s0[c], AL=S->sL[c];
          s += qq[u*3+0]*(T-AL) + qq[u*3+1]*T + qq[u*3+2]*(T-A0);
        }
      }
      S->part[tid]=s;
    } else if(tid>=384 && tid<392){
      int c2=tid-384;
      float s=0;
      for(int c1=0;c1<4;c1++){
        float T=S->totA_s[c1], A0=a0A[b*4+c1], AL=aLA[b*4+c1];
        const float* w=&tA_w2[(c2*4+c1)*3];
        s += w[0]*(T-AL) + w[1]*T + w[2]*(T-A0);
      }
      S->t1_s[c2]=s*invL;
    }
    __syncthreads();
    if(tid<128) S->te_s[tid]=(S->part[tid]+S->part[tid+128])*invL*scB;
    __syncthreads();
    // ---- GATE: wait for all 108 producer blocks (acquire) ----
    if(tid==0){
      while(__hip_atomic_load(&cnt[0],__ATOMIC_ACQUIRE,__HIP_MEMORY_SCOPE_AGENT)<108)
        __builtin_amdgcn_s_sleep(8);
    }
    __syncthreads();
    // f1 + iered in one parallel phase
    if(tid<8) S->f1[tid]=S->t1_s[tid];
    else if(tid<16){
      int f=tid-8;
      float s=0;
#pragma unroll
      for(int g=0;g<24;g++) s+=i1part[(b*24+g)*8+f];
      S->f1[tid]=s;
    } else if(tid>=256 && tid<384){
      int c=tid-256;
      float s=0;
#pragma unroll 8
      for(int g=0;g<24;g++) s+=iepart[(b*24+g)*128+c];
      S->fbuf[128+c]=s;
    }
    __syncthreads();
    if(tid<64){
      float s=at_b1[lane];
#pragma unroll
      for(int i=0;i<16;i++) s+=S->f1[i]*at_w1[i*64+lane];
      float mu=wave_sum64(s)*(1.f/64.f);
      float d=s-mu;
      float var=wave_sum64(d*d)*(1.f/64.f);
      S->h[lane]=fmaxf(d*(1.0f/sqrtf(var+1e-5f))*at_ln_g[lane]+at_ln_b[lane],0.f);
    }
    __syncthreads();
    if(tid<256){
      int n=tid&127, h2=tid>>7;
      float a0=0,a1=0;
      for(int k=h2*32;k<h2*32+32;k+=2){
        a0+=S->h[k]*at_w2[k*128+n];
        a1+=S->h[k+1]*at_w2[(k+1)*128+n];
      }
      S->part[tid]=a0+a1;
    }
    __syncthreads();
    if(tid<128) S->tif[tid]=at_b2[tid]+S->part[tid]+S->part[tid+128];
    __syncthreads();
    if(tid<8){
      int f=tid;
      float ss=0; for(int e=0;e<16;e++){float v=S->tif[e*8+f]; ss+=v*v;}
      S->tden[f]=fmaxf(sqrtf(ss),1e-8f);
    } else if(tid<12){
      int t=tid-8;
      float ss=0; for(int e=0;e<16;e++){float v=protos[t*16+e]; ss+=v*v;}
      S->pden[t]=fmaxf(sqrtf(ss),1e-8f);
    }
    __syncthreads();
    if(tid<128) S->tifn[tid]=S->tif[tid]/S->tden[tid&7];
    if(tid<64) S->pn[tid]=protos[tid]/S->pden[tid>>4];
    __syncthreads();
    if(tid<32){
      int f=tid>>2, t=tid&3;
      float ss=0;
#pragma unroll
      for(int e=0;e<16;e++) ss+=S->pn[t*16+e]*S->tifn[e*8+f];
      float u=jax_uniform128(b*32+f*4+t);
      float g=-logf(-logf(u));
      S->z[tid]=ss+g;
    }
    __syncthreads();
    if(tid<8){
      float best=S->z[tid*4]; int bi=0;
      for(int t=1;t<4;t++){ float v=S->z[tid*4+t]; if(v>best){best=v;bi=t;} }
      S->sidx[tid]=bi;
    }
    __syncthreads();
    if(tid<4){
      int t=tid;
      int fi=0;
      for(int f=7;f>=0;f--) if(S->sidx[f]==t) fi=f;
      S->sfirst[t]=fi;
    } else if(tid<12){
      int f=tid-4;
      int c=0; for(int f2=0;f2<f;f2++) if(S->sidx[f2]==S->sidx[f]) c++;
      S->srank[f]=c;
    }
    __syncthreads();

    if(tid<128) S->fbuf[tid]=S->te_s[tid];
    __syncthreads();
    if(tid<256){
      int l64=tid&63, q=tid>>6;
      float a0=0,a1=0,a2=0,a3=0;
      for(int k=q*64;k<q*64+64;k+=4){
        a0+=S->fbuf[k]  *bv_w1[k*64+l64];
        a1+=S->fbuf[k+1]*bv_w1[(k+1)*64+l64];
        a2+=S->fbuf[k+2]*bv_w1[(k+2)*64+l64];
        a3+=S->fbuf[k+3]*bv_w1[(k+3)*64+l64];
      }
      S->part[tid]=((a0+a1)+(a2+a3));
    }
    __syncthreads();
    if(tid<64){
      float s=bv_b1[lane]+S->part[lane]+S->part[64+lane]+S->part[128+lane]+S->part[192+lane];
      float mu=wave_sum64(s)*(1.f/64.f);
      float d=s-mu;
      float var=wave_sum64(d*d)*(1.f/64.f);
      S->hh[lane]=fmaxf(d*(1.0f/sqrtf(var+1e-5f))*bv_ln_g[lane]+bv_ln_b[lane],0.f);
    }
    __syncthreads();
    {
      int n=tid&255, h2=tid>>8;
      float a0=0,a1=0;
      for(int k=h2*32;k<h2*32+32;k+=2){
        a0+=S->hh[k]*bv_w2[k*256+n];
        a1+=S->hh[k+1]*bv_w2[(k+1)*256+n];
      }
      S->part[tid]=a0+a1;
    }
    __syncthreads();
    if(tid<256) S->ffn_s[tid]=bv_b2[tid]+S->part[tid]+S->part[tid+256];
    __syncthreads();
    if(tid<64){
      float sq=0;
#pragma unroll
      for(int u=0;u<4;u++){ float v=S->ffn_s[u*64+lane]; sq+=v*v; }
      sq=wave_sum64(sq);
      if(lane==0) S->finv_s=1.0f/fmaxf(sqrtf(sq),1e-12f);
    }
    __syncthreads();
    if(tid<256) S->ffn_s[tid]*=S->finv_s;
    __syncthreads();

    if(tid<128){
      int it=tid&63, h2=tid>>6;
      int t=it>>4, v=it&15;
      int tt=S->sidx[S->sfirst[t]];
      const float4* row=(const float4*)(bank+(tt*16+v)*256);
      float sa=0,na=0;
      for(int d4=h2*32;d4<h2*32+32;d4++){
        float4 r=row[d4];
        const float* fp=&S->ffn_s[d4*4];
        sa+=fp[0]*r.x+fp[1]*r.y+fp[2]*r.z+fp[3]*r.w;
        na+=r.x*r.x+r.y*r.y+r.z*r.z+r.w*r.w;
      }
      S->part[tid]=sa;
      S->part[256+tid]=na;
    }
    __syncthreads();
    if(tid<64) S->scores[tid]=(S->part[tid]+S->part[tid+64])/fmaxf(sqrtf(S->part[256+tid]+S->part[320+tid]),1e-12f);
    __syncthreads();
    if(tid<4){
      const float* sc=&S->scores[tid*16];
      unsigned used=0;
      for(int pk=0;pk<16;pk++){
        int best=-1; float bv=-1e30f;
        for(int v2=0;v2<16;v2++){
          if(used&(1u<<v2)) continue;
          float vv=sc[v2];
          if(best<0||vv>bv){bv=vv;best=v2;}
        }
        used|=1u<<best;
        S->order[tid*16+pk]=best;
      }
    }
    __syncthreads();
    if(tid<8){
      int t=S->sidx[tid];
      int v=S->order[t*16+S->srank[tid]];
      S->rows[tid]=t*16+v;
      idxo[b*8+tid]=t;
    }
    __syncthreads();

    for(int ii=tid;ii<2048;ii+=512){
      int r=ii>>8, d=ii&255;
      S->bvf[ii]=bank[S->rows[r]*256+d];
    }
    __syncthreads();
    {
      int r=wv;
      const float* bp=&S->bvf[r*256];
      float a0=0,a1=0,a2=0,a3=0;
      float c0=0,c1=0,c2=0,c3=0;
      for(int d=0;d<256;d+=4){
        float b0=bp[d],b1=bp[d+1],b2=bp[d+2],b3=bp[d+3];
        a0+=b0*m1_w1[d*64+lane];
        a1+=b1*m1_w1[(d+1)*64+lane];
        a2+=b2*m1_w1[(d+2)*64+lane];
        a3+=b3*m1_w1[(d+3)*64+lane];
        c0+=b0*m3_w1[d*64+lane];
        c1+=b1*m3_w1[(d+1)*64+lane];
        c2+=b2*m3_w1[(d+2)*64+lane];
        c3+=b3*m3_w1[(d+3)*64+lane];
      }
      float s1=m1_b1[lane]+((a0+a1)+(a2+a3));
      float s3=m3_b1[lane]+((c0+c1)+(c2+c3));
      float mu=wave_sum64(s1)*(1.f/64.f);
      float dd=s1-mu;
      float var=wave_sum64(dd*dd)*(1.f/64.f);
      hid1[(b*8+r)*64+lane]=fmaxf(dd*(1.0f/sqrtf(var+1e-5f))*m1_g[lane]+m1_bb[lane],0.f);
      mu=wave_sum64(s3)*(1.f/64.f);
      dd=s3-mu;
      var=wave_sum64(dd*dd)*(1.f/64.f);
      hid3[(b*8+r)*64+lane]=fmaxf(dd*(1.0f/sqrtf(var+1e-5f))*m3_g[lane]+m3_bb[lane],0.f);
    }
  }
}

// ---------------- k_heads (wcol loads issued before hl staging) ----------------
__global__ __launch_bounds__(256) void k_heads(const float* __restrict__ hid1, const float* __restrict__ hid3,
                        const float* __restrict__ w2a, const float* __restrict__ b2a,
                        const float* __restrict__ w2b, const float* __restrict__ b2b,
                        unsigned short* __restrict__ A1, unsigned short* __restrict__ A3){
  __shared__ float hl[2048];
  if(blockIdx.x<16){
    int n=blockIdx.x*256+threadIdx.x;
    float wcol[64];
#pragma unroll
    for(int k=0;k<64;k++) wcol[k]=w2a[k*4096+n];
    float bb=b2a[n];
    for(int i=threadIdx.x;i<2048;i+=256) hl[i]=hid1[i];
    __syncthreads();
    for(int bf=0;bf<32;bf++){
      float s=bb;
#pragma unroll
      for(int k=0;k<64;k++) s+=hl[bf*64+k]*wcol[k];
      A1[bf*4096+n]=f2bf(s);
    }
  } else {
    int n=(blockIdx.x-16)*256+threadIdx.x;
    float wcol[64];
#pragma unroll
    for(int k=0;k<64;k++) wcol[k]=w2b[(size_t)k*36864+n];
    float bb=b2b[n];
    for(int i=threadIdx.x;i<2048;i+=256) hl[i]=hid3[i];
    __syncthreads();
    int o=n/576, rem=n-o*576;
    int c=rem/9, tap=rem-c*9;
    size_t base=((size_t)tap*64+o)*64+c;
    for(int bf=0;bf<32;bf++){
      float s=bb;
#pragma unroll
      for(int k=0;k<64;k++) s+=hl[bf*64+k]*wcol[k];
      A3[(size_t)bf*9*4096+base]=f2bf(s);
    }
  }
}

// ---------------- fused dynamic conv: LDS-staged image slab, 512 thr, f-halves, zc+residual ----------------
__global__ __launch_bounds__(512) void k_dynF(const unsigned short* __restrict__ imgTP,
                       const unsigned short* __restrict__ A1, const unsigned short* __restrict__ A3,
                       const int* __restrict__ idx, const float* __restrict__ bn,
                       const float* __restrict__ zc_w, const float* __restrict__ zc_b,
                       const float* __restrict__ img, float* __restrict__ out){
  int blk=blockIdx.x;
  int b=blk/48, r0=blk-b*48;
  int tid=threadIdx.x;
  int lane=tid&63, w8=tid>>6;
  int mt=w8&3, fh=w8>>2;
  int n0=lane&15, kg=lane>>4;
  __shared__ unsigned short slab[7*54*SLABP];
  __shared__ float xl[64*50];
  __shared__ float zl[4096];
  // hoisted: idx + bn params issued before staging so the tt-branch doesn't stall post-barrier
  int tts[4];
#pragma unroll
  for(int i=0;i<4;i++) tts[i]=idx[b*8+fh*4+i];
  int obase=mt*16+kg*4;
  float scale[4],m_[4],be_[4];
#pragma unroll
  for(int reg=0;reg<4;reg++){
    int o=obase+reg;
    scale[reg]=bn[o]/sqrtf(bn[192+o]+1e-5f);
    m_[reg]=bn[128+o]; be_[reg]=bn[64+o];
  }
  for(int i=tid;i<4096;i+=512) zl[i]=zc_w[i];
  for(int i=tid;i<3200;i+=512) xl[i]=0.f;
  {
    const unsigned short* ibase=imgTP+((size_t)b*PHW+(size_t)r0*PP)*64;
    for(int e=tid;e<7*54*8;e+=512){
      int rr=e/(54*8), rem=e-rr*54*8, w=rem>>3, ck=rem&7;
      uint4 v=*(const uint4*)(ibase + ((size_t)(rr*PP+w))*64 + ck*8);
      *(uint4*)(slab + (rr*54+w)*SLABP + ck*8)=v;
    }
  }
  __syncthreads();
  float xsum[3][4];
#pragma unroll
  for(int wc=0;wc<3;wc++)
#pragma unroll
    for(int reg=0;reg<4;reg++) xsum[wc][reg]=0.f;
#pragma unroll
  for(int fi=0;fi<4;fi++){
    int f=fh*4+fi;
    int bf=b*8+f;
    int tt=tts[fi];
    floatx4 acc[3];
#pragma unroll
    for(int i=0;i<3;i++) acc[i]=(floatx4){0.f,0.f,0.f,0.f};
    if(tt==0){
      const unsigned short* Ab=A1+(size_t)bf*4096;
#pragma unroll
      for(int c0=0;c0<64;c0+=32){
        short8 a=*(const short8*)(Ab+((mt*16+n0)*64+c0+kg*8));
#pragma unroll
        for(int wc=0;wc<3;wc++){
          short8 bv=*(const short8*)(slab + (3*54 + wc*16+n0+3)*SLABP + c0+kg*8);
          acc[wc]=__builtin_amdgcn_mfma_f32_16x16x32_bf16(a,bv,acc[wc],0,0,0);
        }
      }
    } else {
      int d=tt;
      const unsigned short* A3b=A3+(size_t)bf*9*4096;
#pragma unroll
      for(int ti=0;ti<3;ti++){
        int lr=d*(ti-1)+3;
#pragma unroll
        for(int tj=0;tj<3;tj++){
          int tap=ti*3+tj;
          int dw=d*(tj-1)+3;
          const unsigned short* Ab=A3b+(size_t)tap*4096;
#pragma unroll
          for(int c0=0;c0<64;c0+=32){
            short8 a=*(const short8*)(Ab+((mt*16+n0)*64+c0+kg*8));
#pragma unroll
            for(int wc=0;wc<3;wc++){
              short8 bv=*(const short8*)(slab + (lr*54 + wc*16+n0+dw)*SLABP + c0+kg*8);
              acc[wc]=__builtin_amdgcn_mfma_f32_16x16x32_bf16(a,bv,acc[wc],0,0,0);
            }
          }
        }
      }
    }
#pragma unroll
    for(int wc=0;wc<3;wc++)
#pragma unroll
      for(int reg=0;reg<4;reg++)
        xsum[wc][reg]+=leaky((acc[wc][reg]-m_[reg])*scale[reg]+be_[reg]);
  }
#pragma unroll
  for(int wc=0;wc<3;wc++)
#pragma unroll
    for(int reg=0;reg<4;reg++)
      atomicAdd(&xl[(obase+reg)*50 + wc*16+n0], xsum[wc][reg]*0.125f);
  __syncthreads();
  size_t base=(size_t)b*64*HW + r0*48;
  for(int e=tid;e<3072;e+=512){
    int o=e/48, px=e-o*48;
    float s=zc_b[o];
#pragma unroll
    for(int c=0;c<64;c++) s+=zl[o*64+c]*xl[c*50+px];
    size_t a=base+(size_t)o*HW+px;
    out[a]=s+img[a];
  }
}

extern "C" void kernel_launch(void* const* d_in, const int* in_sizes, int n_in,
                              void* d_out, int out_size, void* d_ws, size_t ws_size,
                              hipStream_t stream){
  const float* bank   =(const float*)d_in[0];
  const float* task_f =(const float*)d_in[1];
  const float* img_f  =(const float*)d_in[2];
  const float* protos =(const float*)d_in[3];
  const float* tA_w1  =(const float*)d_in[4];
  const float* tA_w2  =(const float*)d_in[5];
  const float* iA_w   =(const float*)d_in[6];
  const float* iA_bn  =(const float*)d_in[7];
  const float* at_w1  =(const float*)d_in[8];
  const float* at_b1  =(const float*)d_in[9];
  const float* at_ln_g=(const float*)d_in[10];
  const float* at_ln_b=(const float*)d_in[11];
  const float* at_w2  =(const float*)d_in[12];
  const float* at_b2  =(const float*)d_in[13];
  const float* bv_t1  =(const float*)d_in[14];
  const float* bv_t2  =(const float*)d_in[15];
  const float* bv_ic1 =(const float*)d_in[16];
  const float* bv_bn1 =(const float*)d_in[17];
  const float* bv_ic2 =(const float*)d_in[18];
  const float* bv_bn2 =(const float*)d_in[19];
  const float* bv_w1  =(const float*)d_in[20];
  const float* bv_b1  =(const float*)d_in[21];
  const float* bv_ln_g=(const float*)d_in[22];
  const float* bv_ln_b=(const float*)d_in[23];
  const float* bv_w2  =(const float*)d_in[24];
  const float* bv_b2  =(const float*)d_in[25];
  const float* m1_w1  =(const float*)d_in[26];
  const float* m1_b1  =(const float*)d_in[27];
  const float* m1_ln_g=(const float*)d_in[28];
  const float* m1_ln_b=(const float*)d_in[29];
  const float* m1_w2  =(const float*)d_in[30];
  const float* m1_b2  =(const float*)d_in[31];
  const float* m3_w1  =(const float*)d_in[32];
  const float* m3_b1  =(const float*)d_in[33];
  const float* m3_ln_g=(const float*)d_in[34];
  const float* m3_ln_b=(const float*)d_in[35];
  const float* m3_w2  =(const float*)d_in[36];
  const float* m3_b2  =(const float*)d_in[37];
  const float* blr_bn =(const float*)d_in[38];
  const float* zc_w   =(const float*)d_in[39];
  const float* zc_b   =(const float*)d_in[40];

  float* ws=(float*)d_ws;
  // all accumulators are per-block partial slots -> no zero-init needed anywhere
  float* totApart=ws+0;        // 4*64*4            [0,1024)
  float* a0A  =ws+1024;        // 16
  float* aLA  =ws+1040;        // 16
  float* totBpart=ws+1056;     // 4*64*64           [1056,17440)
  float* a0B  =ws+17440;       // 256
  float* aLB  =ws+17696;       // 256
  float* rmspart=ws+17952;     // 256
  float* i1part =ws+18208;     // 4*24*8 = 768
  float* iepart =ws+18976;     // 4*24*128 = 12288  [18976,31264)
  int*   idxp   =(int*)(ws+31264);                  // 32
  float* hid1=ws+31296;        // 2048
  float* hid3=ws+33344;        // 2048 -> ends 35392
  unsigned short* A1p  =(unsigned short*)(ws+35392);     // 131072 bf16  -> ends 100928
  unsigned short* A3p  =(unsigned short*)(ws+100928);    // 1179648 bf16 -> ends 690752
  unsigned short* imgTP=(unsigned short*)(ws+690752);    // 746496 bf16 (padded) -> ends 1064000
  unsigned short* W1Tp =(unsigned short*)(ws+1064000);   // 36864 bf16 -> ends 1082432
  unsigned short* W2Tp =(unsigned short*)(ws+1082432);   // 73728 bf16 -> ends 1119296
  unsigned short* WATp =(unsigned short*)(ws+1119296);   // 9216 bf16 -> ends 1123904
  float* warm =ws+1123904;                               // 1024 f dummy sink
  int*   cnt  =(int*)(ws+1124928);                       // 4 ints, zeroed by k_pre
  // total ~4.5 MB

  k_pre<<<948,256,0,stream>>>(task_f, tA_w1, bv_t1,
                              totApart, a0A, aLA, totBpart, a0B, aLB, rmspart,
                              img_f, bv_ic1, bv_ic2, iA_w, imgTP, W1Tp, W2Tp, WATp,
                              m1_w1, m3_w1, bv_w1, bv_w2, bv_t2, at_w2, bank,
                              m1_w2, m3_w2, zc_w, warm, cnt);
  k_cm<<<112,512,0,stream>>>(imgTP, W1Tp, W2Tp, WATp, bv_bn1, bv_bn2, iA_bn,
                             iepart, i1part,
                             totApart, a0A, aLA, totBpart, a0B, aLB, rmspart,
                             tA_w2, bv_t2,
                             at_w1, at_b1, at_ln_g, at_ln_b, at_w2, at_b2, protos,
                             bv_w1, bv_b1, bv_ln_g, bv_ln_b, bv_w2, bv_b2, bank,
                             m1_w1, m1_b1, m1_ln_g, m1_ln_b,
                             m3_w1, m3_b1, m3_ln_g, m3_ln_b,
                             idxp, hid1, hid3, cnt);
  k_heads<<<160,256,0,stream>>>(hid1, hid3, m1_w2, m1_b2, m3_w2, m3_b2, A1p, A3p);
  k_dynF<<<192,512,0,stream>>>(imgTP, A1p, A3p, idxp, blr_bn, zc_w, zc_b, img_f, (float*)d_out);

  (void)in_sizes; (void)n_in; (void)out_size; (void)ws_size;
}